// Round 6
// baseline (148.328 us; speedup 1.0000x reference)
//
#include <hip/hip_runtime.h>
#include <hip/hip_bf16.h>

// LCN spiking net, round 6: ONE kernel, one block per row, all-LDS chain.
//  - Spiking update is identity; only t=T-1 matters -> 32 rows, rows fully
//    independent -> no grid sync needed anywhere.
//  - Round 1 (same shape) was 103us ONLY because layer 0 gathered from
//    global (random 64-lane gather = ~60 L1-line splits per wave). Fix:
//    stage the 57.6KB x-row in LDS first (validated fast in round 3), so
//    every gather in the net is an LDS read (~9 cyc/wave amortized).
//  - Round 4 lesson: grid barriers cost ~35us on gfx950 -> everything in one
//    block per row, __syncthreads only.
//  - Rounds 3/5 lesson: each dispatch boundary ~2-4us; 6 dispatches was
//    ~30us total. One dispatch, no memset (each out element stored once).
//  - LDS aliasing: bufX[14400] holds x, then h2(3600)+h4(900); bufH[7200]
//    holds h1, then h3(1800)+h5(450). Peak 86.4KB.
//  - Remaining time is the harness reset floor (~99us: 268MB ws poison at
//    ~42us + input restore) — untouchable from kernel code.

#define ROWS 32
#define TSTEPS 20
#define D0 14400
#define D1 7200
#define D2 3600
#define D3 1800
#define D4 900
#define D5 450
#define KNB 25

__device__ __forceinline__ void lds_layer(const float* __restrict__ sin,
                                          float* __restrict__ sout,
                                          const float* __restrict__ w,
                                          const float* __restrict__ bvec,
                                          const int* __restrict__ knn,
                                          int dout)
{
#pragma unroll 1
    for (int j = threadIdx.x; j < dout; j += 1024) {
        const int*   kn = knn + j * KNB;
        const float* ww = w   + j * KNB;
        float acc = bvec[j];
#pragma unroll
        for (int k = 0; k < KNB; ++k)
            acc += sin[kn[k]] * ww[k];
        sout[j] = acc;
    }
    __syncthreads();
}

__global__ __launch_bounds__(1024)
void lcn_row(const float* __restrict__ x,
             const float* __restrict__ w0, const float* __restrict__ b0, const int* __restrict__ knn0,
             const float* __restrict__ w1, const float* __restrict__ b1, const int* __restrict__ knn1,
             const float* __restrict__ w2, const float* __restrict__ b2, const int* __restrict__ knn2,
             const float* __restrict__ w3, const float* __restrict__ b3, const int* __restrict__ knn3,
             const float* __restrict__ w4, const float* __restrict__ b4, const int* __restrict__ knn4,
             const float* __restrict__ Wfc, const float* __restrict__ bfc,
             float* __restrict__ out)
{
    __shared__ float bufX[D0];   // 57.6 KB: x, then h2 (0..3599), h4 (4096..4995)
    __shared__ float bufH[D1];   // 28.8 KB: h1, then h3 (0..1799), h5 (2048..2497)

    const int row = blockIdx.x;
    const float* xrow = x + ((size_t)row * TSTEPS + (TSTEPS - 1)) * (size_t)D0;

    // stage x row: coalesced float4, 4 iters/thread
    {
        const float4* src = reinterpret_cast<const float4*>(xrow);
        float4* dst = reinterpret_cast<float4*>(bufX);
#pragma unroll 1
        for (int i = threadIdx.x; i < D0 / 4; i += 1024)
            dst[i] = src[i];
    }
    __syncthreads();

    float* h1 = bufH;          // 7200
    float* h2 = bufX;          // 3600 (x dead after layer0)
    float* h3 = bufH;          // 1800 (h1 dead after layer1)
    float* h4 = bufX + 4096;   // 900  (disjoint from h3 reads; h2 dead after layer2)
    float* h5 = bufH + 2048;   // 450  (disjoint from h4; h3 dead after layer3)

    lds_layer(bufX, h1, w0, b0, knn0, D1);   // 14400 -> 7200
    lds_layer(h1,   h2, w1, b1, knn1, D2);   //  7200 -> 3600
    lds_layer(h2,   h3, w2, b2, knn2, D3);   //  3600 -> 1800
    lds_layer(h3,   h4, w3, b3, knn3, D4);   //  1800 ->  900
    lds_layer(h4,   h5, w4, b4, knn4, D5);   //   900 ->  450

    // FC: out[row][o] = bfc[o] + sum_i h5[i] * Wfc[i*2+o]; waves 0-1, o = wid
    const int lane = threadIdx.x & 63;
    const int wid  = threadIdx.x >> 6;
    if (wid < 2) {
        float p = 0.0f;
#pragma unroll 1
        for (int i = lane; i < D5; i += 64)
            p += h5[i] * Wfc[i * 2 + wid];
#pragma unroll
        for (int off = 32; off; off >>= 1)
            p += __shfl_down(p, off, 64);
        if (lane == 0)
            out[row * 2 + wid] = p + bfc[wid];
    }
}

extern "C" void kernel_launch(void* const* d_in, const int* in_sizes, int n_in,
                              void* d_out, int out_size, void* d_ws, size_t ws_size,
                              hipStream_t stream)
{
    const float* x    = (const float*)d_in[0];
    const float* w0   = (const float*)d_in[1];
    const float* b0   = (const float*)d_in[2];
    const int*   knn0 = (const int*)  d_in[3];
    const float* w1   = (const float*)d_in[4];
    const float* b1   = (const float*)d_in[5];
    const int*   knn1 = (const int*)  d_in[6];
    const float* w2   = (const float*)d_in[7];
    const float* b2   = (const float*)d_in[8];
    const int*   knn2 = (const int*)  d_in[9];
    const float* w3   = (const float*)d_in[10];
    const float* b3   = (const float*)d_in[11];
    const int*   knn3 = (const int*)  d_in[12];
    const float* w4   = (const float*)d_in[13];
    const float* b4   = (const float*)d_in[14];
    const int*   knn4 = (const int*)  d_in[15];
    const float* Wfc  = (const float*)d_in[16];
    const float* bfc  = (const float*)d_in[17];
    float* out = (float*)d_out;

    lcn_row<<<dim3(ROWS), dim3(1024), 0, stream>>>(
        x,
        w0, b0, knn0,
        w1, b1, knn1,
        w2, b2, knn2,
        w3, b3, knn3,
        w4, b4, knn4,
        Wfc, bfc,
        out);
}

// Round 7
// 133.480 us; speedup vs baseline: 1.1112x; 1.1112x over previous
//
#include <hip/hip_runtime.h>
#include <hip/hip_bf16.h>

// LCN spiking net, round 7: round-5 structure (wide + transposed), fewer
// dispatches, leaner layer 0.
//  - Spiking update is identity; only t=T-1 matters -> 32 rows.
//  - Round 6 lesson: one-block-per-row all-LDS concentrates ~6000 ds_reads
//    on 32 CU LDS pipes (~5.8cyc each + random conflicts) -> 44us. Wide
//    transposed global gathers spread the same work over 256 CUs' L2 paths.
//  - Round 4 lesson: grid barriers ~35us each -> multi-dispatch.
//  - This round: 6 dispatches -> 4. Tail (L3+L4+FC) is one block/row writing
//    out directly (no atomics, no memset); per-block LDS load there is only
//    ~50 ds_reads/wave, far below the round-6 regime. l0_stage uses 4
//    blocks/row (7.4MB staged vs 14.7MB) with 512 threads.

#define ROWS 32
#define TSTEPS 20
#define D0 14400
#define D1 7200
#define D2 3600
#define D3 1800
#define D4 900
#define D5 450
#define KNB 25

// K1: layer 0. Grid (4, ROWS), 512 threads. Stage x row in LDS, gather 1800
// outputs, write h1t transposed.
__global__ __launch_bounds__(512)
void l0_stage(const float* __restrict__ x, float* __restrict__ h1t,
              const float* __restrict__ w, const float* __restrict__ bvec,
              const int* __restrict__ knn)
{
    __shared__ float s[D0];   // 57.6 KB
    const int r = blockIdx.y;
    const float* xrow = x + ((size_t)r * TSTEPS + (TSTEPS - 1)) * (size_t)D0;

    const float4* src = reinterpret_cast<const float4*>(xrow);
    float4* dst = reinterpret_cast<float4*>(s);
#pragma unroll 1
    for (int i = threadIdx.x; i < D0 / 4; i += 512)
        dst[i] = src[i];
    __syncthreads();

    const int j0 = blockIdx.x * (D1 / 4);   // 1800 outputs per block
#pragma unroll 1
    for (int j = j0 + threadIdx.x; j < j0 + D1 / 4; j += 512) {
        const int*   kn = knn + j * KNB;
        const float* ww = w   + j * KNB;
        float acc = bvec[j];
#pragma unroll
        for (int k = 0; k < KNB; ++k)
            acc += s[kn[k]] * ww[k];
        h1t[(j << 5) + r] = acc;   // transposed write
    }
}

// Transposed gather layer: pout[j][r] = b[j] + sum_k pin[knn[j][k]][r]*w[j][k]
// Wave = 2 outputs x 32 rows; each gather touches 2 contiguous 128B lines.
__global__ __launch_bounds__(256)
void layer_t_k(const float* __restrict__ pin, float* __restrict__ pout,
               const float* __restrict__ w, const float* __restrict__ bvec,
               const int* __restrict__ knn, int npairs)
{
    const int lane = threadIdx.x & 63;
    const int r  = lane & 31;
    const int jj = lane >> 5;
    const int nw = gridDim.x << 2;
#pragma unroll 1
    for (int jp = (blockIdx.x << 2) + (threadIdx.x >> 6); jp < npairs; jp += nw) {
        const int j = (jp << 1) + jj;
        const int*   kn = knn + j * KNB;
        const float* ww = w   + j * KNB;
        float acc = bvec[j];
#pragma unroll
        for (int k = 0; k < KNB; ++k)
            acc += pin[(kn[k] << 5) + r] * ww[k];
        pout[(j << 5) + r] = acc;
    }
}

// K4: tail = layer3 (1800->900) + layer4 (900->450) + FC (450->2).
// One block per row; stage h3 row from h3t, short LDS chains, direct store.
__global__ __launch_bounds__(1024)
void tail32(const float* __restrict__ h3t,
            const float* __restrict__ w3, const float* __restrict__ b3, const int* __restrict__ knn3,
            const float* __restrict__ w4, const float* __restrict__ b4, const int* __restrict__ knn4,
            const float* __restrict__ Wfc, const float* __restrict__ bfc,
            float* __restrict__ out)
{
    __shared__ float s3[D3];
    __shared__ float s4[D4];
    __shared__ float s5[D5];

    const int r = blockIdx.x;

    // stage h3 row: s3[i] = h3t[i*32 + r] (strided reads, 1800 loads, 16 waves)
#pragma unroll 1
    for (int i = threadIdx.x; i < D3; i += 1024)
        s3[i] = h3t[(i << 5) + r];
    __syncthreads();

    if (threadIdx.x < D4) {
        const int j = threadIdx.x;
        const int*   kn = knn3 + j * KNB;
        const float* ww = w3   + j * KNB;
        float acc = b3[j];
#pragma unroll
        for (int k = 0; k < KNB; ++k)
            acc += s3[kn[k]] * ww[k];
        s4[j] = acc;
    }
    __syncthreads();

    if (threadIdx.x < D5) {
        const int j = threadIdx.x;
        const int*   kn = knn4 + j * KNB;
        const float* ww = w4   + j * KNB;
        float acc = b4[j];
#pragma unroll
        for (int k = 0; k < KNB; ++k)
            acc += s4[kn[k]] * ww[k];
        s5[j] = acc;
    }
    __syncthreads();

    const int lane = threadIdx.x & 63;
    const int wid  = threadIdx.x >> 6;
    if (wid < 2) {
        float p = 0.0f;
#pragma unroll 1
        for (int i = lane; i < D5; i += 64)
            p += s5[i] * Wfc[i * 2 + wid];
#pragma unroll
        for (int off = 32; off; off >>= 1)
            p += __shfl_down(p, off, 64);
        if (lane == 0)
            out[r * 2 + wid] = p + bfc[wid];
    }
}

extern "C" void kernel_launch(void* const* d_in, const int* in_sizes, int n_in,
                              void* d_out, int out_size, void* d_ws, size_t ws_size,
                              hipStream_t stream)
{
    const float* x    = (const float*)d_in[0];
    const float* w0   = (const float*)d_in[1];
    const float* b0   = (const float*)d_in[2];
    const int*   knn0 = (const int*)  d_in[3];
    const float* w1   = (const float*)d_in[4];
    const float* b1   = (const float*)d_in[5];
    const int*   knn1 = (const int*)  d_in[6];
    const float* w2   = (const float*)d_in[7];
    const float* b2   = (const float*)d_in[8];
    const int*   knn2 = (const int*)  d_in[9];
    const float* w3   = (const float*)d_in[10];
    const float* b3   = (const float*)d_in[11];
    const int*   knn3 = (const int*)  d_in[12];
    const float* w4   = (const float*)d_in[13];
    const float* b4   = (const float*)d_in[14];
    const int*   knn4 = (const int*)  d_in[15];
    const float* Wfc  = (const float*)d_in[16];
    const float* bfc  = (const float*)d_in[17];
    float* out = (float*)d_out;

    // transposed intermediates in ws (floats): h1t[D1][32] | h2t[D2][32] | h3t[D3][32]
    float* h1t = (float*)d_ws;
    float* h2t = h1t + (size_t)D1 * ROWS;
    float* h3t = h2t + (size_t)D2 * ROWS;

    // K1: layer 0, x[:,T-1,:] -> h1t   (4 blocks/row)
    l0_stage<<<dim3(4, ROWS), dim3(512), 0, stream>>>(x, h1t, w0, b0, knn0);

    // K2: layer 1, h1t -> h2t  (1800 pairs, 1 pair/wave)
    layer_t_k<<<dim3(450), dim3(256), 0, stream>>>(h1t, h2t, w1, b1, knn1, D2 / 2);

    // K3: layer 2, h2t -> h3t  (900 pairs)
    layer_t_k<<<dim3(225), dim3(256), 0, stream>>>(h2t, h3t, w2, b2, knn2, D3 / 2);

    // K4: layers 3+4+FC, one block per row, direct store to out
    tail32<<<dim3(ROWS), dim3(1024), 0, stream>>>(
        h3t, w3, b3, knn3, w4, b4, knn4, Wfc, bfc, out);
}

// Round 8
// 129.871 us; speedup vs baseline: 1.1421x; 1.0278x over previous
//
#include <hip/hip_runtime.h>
#include <hip/hip_bf16.h>

// LCN spiking net, round 8: best-of-all-rounds hybrid.
//  - Spiking update is identity; only t=T-1 matters -> 32 rows.
//  - Measured lessons:
//    R4: grid barriers ~35us each on gfx950 -> multi-dispatch only.
//    R6: random LDS gathers ~20cyc/wave-gather -> keep big layers as
//        transposed GLOBAL gathers (2x128B coalesced, L2-served, all CUs).
//    R7: strided global READS in the tail stall (64 lines/wave-load);
//        scatter WRITES are fire-and-forget -> L2 kernel writes h3 row-major
//        so the tail stages coalesced.
//    R5/R7: l0 must stay 8 blocks/row (256 CUs); 4/row halves parallelism.
//  - 4 dispatches: l0 (LDS-staged row gather) -> l1t -> l2t(row-major out)
//    -> tail32 (L3+L4+FC, one block/row, ~530 LDS wave-gathers, direct store).

#define ROWS 32
#define TSTEPS 20
#define D0 14400
#define D1 7200
#define D2 3600
#define D3 1800
#define D4 900
#define D5 450
#define KNB 25

// K1: layer 0. Grid (8, ROWS), 256 threads. Stage x row in LDS, gather 900
// outputs per block, write h1t transposed.
__global__ __launch_bounds__(256)
void l0_stage(const float* __restrict__ x, float* __restrict__ h1t,
              const float* __restrict__ w, const float* __restrict__ bvec,
              const int* __restrict__ knn)
{
    __shared__ float s[D0];   // 57.6 KB
    const int r = blockIdx.y;
    const float* xrow = x + ((size_t)r * TSTEPS + (TSTEPS - 1)) * (size_t)D0;

    const float4* src = reinterpret_cast<const float4*>(xrow);
    float4* dst = reinterpret_cast<float4*>(s);
#pragma unroll 1
    for (int i = threadIdx.x; i < D0 / 4; i += 256)
        dst[i] = src[i];
    __syncthreads();

    const int j0 = blockIdx.x * 900;
#pragma unroll 1
    for (int j = j0 + threadIdx.x; j < j0 + 900; j += 256) {
        const int*   kn = knn + j * KNB;
        const float* ww = w   + j * KNB;
        float acc = bvec[j];
#pragma unroll
        for (int k = 0; k < KNB; ++k)
            acc += s[kn[k]] * ww[k];
        h1t[(j << 5) + r] = acc;   // transposed write
    }
}

// K2: transposed gather layer (h1t -> h2t). Wave = 2 outputs x 32 rows.
__global__ __launch_bounds__(256)
void layer_t_k(const float* __restrict__ pin, float* __restrict__ pout,
               const float* __restrict__ w, const float* __restrict__ bvec,
               const int* __restrict__ knn, int npairs)
{
    const int lane = threadIdx.x & 63;
    const int r  = lane & 31;
    const int jj = lane >> 5;
    const int nw = gridDim.x << 2;
#pragma unroll 1
    for (int jp = (blockIdx.x << 2) + (threadIdx.x >> 6); jp < npairs; jp += nw) {
        const int j = (jp << 1) + jj;
        const int*   kn = knn + j * KNB;
        const float* ww = w   + j * KNB;
        float acc = bvec[j];
#pragma unroll
        for (int k = 0; k < KNB; ++k)
            acc += pin[(kn[k] << 5) + r] * ww[k];
        pout[(j << 5) + r] = acc;
    }
}

// K3: transposed gather layer writing ROW-MAJOR output (h2t -> h3 row-major).
// Scatter stores (64 lines/wave) are fire-and-forget; lets the tail stage
// its input coalesced instead of strided-reading (R7's mistake).
__global__ __launch_bounds__(256)
void layer_t_rm(const float* __restrict__ pin, float* __restrict__ pout_rm,
                const float* __restrict__ w, const float* __restrict__ bvec,
                const int* __restrict__ knn, int npairs, int dout)
{
    const int lane = threadIdx.x & 63;
    const int r  = lane & 31;
    const int jj = lane >> 5;
    const int nw = gridDim.x << 2;
#pragma unroll 1
    for (int jp = (blockIdx.x << 2) + (threadIdx.x >> 6); jp < npairs; jp += nw) {
        const int j = (jp << 1) + jj;
        const int*   kn = knn + j * KNB;
        const float* ww = w   + j * KNB;
        float acc = bvec[j];
#pragma unroll
        for (int k = 0; k < KNB; ++k)
            acc += pin[(kn[k] << 5) + r] * ww[k];
        pout_rm[r * dout + j] = acc;   // row-major scatter store
    }
}

// K4: tail = layer3 (1800->900) + layer4 (900->450) + FC (450->2).
// One block per row, 1024 threads; coalesced stage of h3 row, short LDS
// chains (~530 wave-gathers total), direct store to out.
__global__ __launch_bounds__(1024)
void tail32(const float* __restrict__ h3_rm,
            const float* __restrict__ w3, const float* __restrict__ b3, const int* __restrict__ knn3,
            const float* __restrict__ w4, const float* __restrict__ b4, const int* __restrict__ knn4,
            const float* __restrict__ Wfc, const float* __restrict__ bfc,
            float* __restrict__ out)
{
    __shared__ float s3[D3];
    __shared__ float s4[D4];
    __shared__ float s5[D5];

    const int r = blockIdx.x;
    const float* hrow = h3_rm + (size_t)r * D3;

    // coalesced stage: 1800 floats
#pragma unroll 1
    for (int i = threadIdx.x; i < D3; i += 1024)
        s3[i] = hrow[i];
    __syncthreads();

#pragma unroll 1
    for (int j = threadIdx.x; j < D4; j += 1024) {
        const int*   kn = knn3 + j * KNB;
        const float* ww = w3   + j * KNB;
        float acc = b3[j];
#pragma unroll
        for (int k = 0; k < KNB; ++k)
            acc += s3[kn[k]] * ww[k];
        s4[j] = acc;
    }
    __syncthreads();

#pragma unroll 1
    for (int j = threadIdx.x; j < D5; j += 1024) {
        const int*   kn = knn4 + j * KNB;
        const float* ww = w4   + j * KNB;
        float acc = b4[j];
#pragma unroll
        for (int k = 0; k < KNB; ++k)
            acc += s4[kn[k]] * ww[k];
        s5[j] = acc;
    }
    __syncthreads();

    const int lane = threadIdx.x & 63;
    const int wid  = threadIdx.x >> 6;
    if (wid < 2) {
        float p = 0.0f;
#pragma unroll 1
        for (int i = lane; i < D5; i += 64)
            p += s5[i] * Wfc[i * 2 + wid];
#pragma unroll
        for (int off = 32; off; off >>= 1)
            p += __shfl_down(p, off, 64);
        if (lane == 0)
            out[r * 2 + wid] = p + bfc[wid];
    }
}

extern "C" void kernel_launch(void* const* d_in, const int* in_sizes, int n_in,
                              void* d_out, int out_size, void* d_ws, size_t ws_size,
                              hipStream_t stream)
{
    const float* x    = (const float*)d_in[0];
    const float* w0   = (const float*)d_in[1];
    const float* b0   = (const float*)d_in[2];
    const int*   knn0 = (const int*)  d_in[3];
    const float* w1   = (const float*)d_in[4];
    const float* b1   = (const float*)d_in[5];
    const int*   knn1 = (const int*)  d_in[6];
    const float* w2   = (const float*)d_in[7];
    const float* b2   = (const float*)d_in[8];
    const int*   knn2 = (const int*)  d_in[9];
    const float* w3   = (const float*)d_in[10];
    const float* b3   = (const float*)d_in[11];
    const int*   knn3 = (const int*)  d_in[12];
    const float* w4   = (const float*)d_in[13];
    const float* b4   = (const float*)d_in[14];
    const int*   knn4 = (const int*)  d_in[15];
    const float* Wfc  = (const float*)d_in[16];
    const float* bfc  = (const float*)d_in[17];
    float* out = (float*)d_out;

    // ws (floats): h1t[D1][32] | h2t[D2][32] | h3_rm[32][D3]
    float* h1t   = (float*)d_ws;
    float* h2t   = h1t + (size_t)D1 * ROWS;
    float* h3_rm = h2t + (size_t)D2 * ROWS;

    // K1: layer 0, x[:,T-1,:] -> h1t   (8 blocks/row)
    l0_stage<<<dim3(8, ROWS), dim3(256), 0, stream>>>(x, h1t, w0, b0, knn0);

    // K2: layer 1, h1t -> h2t  (1800 pairs, 1 pair/wave)
    layer_t_k<<<dim3(450), dim3(256), 0, stream>>>(h1t, h2t, w1, b1, knn1, D2 / 2);

    // K3: layer 2, h2t -> h3 row-major  (900 pairs)
    layer_t_rm<<<dim3(225), dim3(256), 0, stream>>>(h2t, h3_rm, w2, b2, knn2, D3 / 2, D3);

    // K4: layers 3+4+FC, one block per row, direct store to out
    tail32<<<dim3(ROWS), dim3(1024), 0, stream>>>(
        h3_rm, w3, b3, knn3, w4, b4, knn4, Wfc, bfc, out);
}